// Round 18
// baseline (169.600 us; speedup 1.0000x reference)
//
#include <hip/hip_runtime.h>

#define N_NODES 50000
#define N_EDGES 800000
#define HDIM    128
#define NGRAPH  8
#define NCLS    5
#define ZROW    50000                                         // zero row in y
#define SCAN_CHUNK 1024
#define NSCANBLK ((N_NODES + SCAN_CHUNK - 1) / SCAN_CHUNK)   // 49
#define NB_GEMM  ((N_NODES + 63) / 64)                        // 782
#define NB_EDGE  ((N_EDGES + 255) / 256)                      // 3125
#define NB_CNT   ((N_EDGES / 8 + 255) / 256)                  // 391
#define NB_PRE   ((N_NODES * HDIM / 8 + 255) / 256)           // 3125

// ---- bf16 helpers (raw ushort storage, fp32 compute) ------------------------
__device__ __forceinline__ float bf2f(ushort u) {
    return __uint_as_float((unsigned int)u << 16);
}
__device__ __forceinline__ ushort f2bf(float f) {
    unsigned int u = __float_as_uint(f);
    u += 0x7FFFu + ((u >> 16) & 1u);      // round-to-nearest-even
    return (ushort)(u >> 16);
}

typedef __attribute__((ext_vector_type(8)))  __bf16 bf16x8;
typedef __attribute__((ext_vector_type(16))) float  f32x16;
typedef __attribute__((ext_vector_type(2)))  float  f32x2;
union BF8 { uint4 q; ushort u[8]; bf16x8 v; };

// ------- zero: cnti + hG (tiny; must precede fused count||pre) ---------------
__global__ __launch_bounds__(256) void k_zero(int* cnti, float* hG) {
    int i = blockIdx.x * blockDim.x + threadIdx.x;
    if (i < N_NODES) cnti[i] = 0;
    if (i < NGRAPH * 2 * HDIM) hG[i] = 0.0f;
}

// ------- fused: blocks [0,NB_CNT) = count+slot (8 edges/thread, FIRST so ----
// ------- atomics start immediately); blocks [NB_CNT,..) = pre (streaming) ----
__global__ __launch_bounds__(256) void k_count_pre(const int* __restrict__ dst,
                                                   int* cnti,
                                                   ushort* __restrict__ slot16,
                                                   const float* __restrict__ x,
                                                   ushort* __restrict__ xb,
                                                   const float* __restrict__ W1,
                                                   const float* __restrict__ W2,
                                                   ushort* __restrict__ Wt1,
                                                   ushort* __restrict__ Wt2,
                                                   unsigned char* __restrict__ y) {
    if (blockIdx.x < NB_CNT) {
        // ---- count path ----
        int e8 = blockIdx.x * 256 + threadIdx.x;
        if (e8 < N_EDGES / 8) {
            int4 d0 = reinterpret_cast<const int4*>(dst)[e8 * 2];
            int4 d1 = reinterpret_cast<const int4*>(dst)[e8 * 2 + 1];
            ushort4 s0, s1;
            s0.x = (ushort)atomicAdd(&cnti[d0.x], 1);
            s0.y = (ushort)atomicAdd(&cnti[d0.y], 1);
            s0.z = (ushort)atomicAdd(&cnti[d0.z], 1);
            s0.w = (ushort)atomicAdd(&cnti[d0.w], 1);
            s1.x = (ushort)atomicAdd(&cnti[d1.x], 1);
            s1.y = (ushort)atomicAdd(&cnti[d1.y], 1);
            s1.z = (ushort)atomicAdd(&cnti[d1.z], 1);
            s1.w = (ushort)atomicAdd(&cnti[d1.w], 1);
            reinterpret_cast<ushort4*>(slot16)[e8 * 2]     = s0;
            reinterpret_cast<ushort4*>(slot16)[e8 * 2 + 1] = s1;
        }
        return;
    }
    // ---- pre path ----
    int i = (blockIdx.x - NB_CNT) * 256 + threadIdx.x;
    if (i < 32) reinterpret_cast<unsigned*>(y + (size_t)ZROW * HDIM)[i] = 0u;
    if (i < HDIM * HDIM) {
        int k = i >> 7, c = i & (HDIM - 1);          // read W[k][c] coalesced
        Wt1[c * HDIM + k] = f2bf(W1[i]);
        Wt2[c * HDIM + k] = f2bf(W2[i]);
    }
    if ((size_t)i * 8 < (size_t)N_NODES * HDIM) {
        float4 f0 = reinterpret_cast<const float4*>(x)[i * 2];
        float4 f1 = reinterpret_cast<const float4*>(x)[i * 2 + 1];
        uint4 o;
        o.x = (unsigned)f2bf(f0.x) | ((unsigned)f2bf(f0.y) << 16);
        o.y = (unsigned)f2bf(f0.z) | ((unsigned)f2bf(f0.w) << 16);
        o.z = (unsigned)f2bf(f1.x) | ((unsigned)f2bf(f1.y) << 16);
        o.w = (unsigned)f2bf(f1.z) | ((unsigned)f2bf(f1.w) << 16);
        reinterpret_cast<uint4*>(xb)[i] = o;
    }
}

// -------- scan step 1: exclusive scan of CEIL8(in-degree) + dinv -------------
__global__ __launch_bounds__(256) void k_scan1(const int* __restrict__ cnti,
                                               int* __restrict__ rowptr,
                                               int* __restrict__ bsum,
                                               float* __restrict__ dinv) {
    __shared__ int wsum[4];
    int tid = threadIdx.x, lane = tid & 63, wid = tid >> 6;
    int i0 = blockIdx.x * SCAN_CHUNK + tid * 4;
    int v[4];
    int tsum = 0;
#pragma unroll
    for (int p = 0; p < 4; ++p) {
        int i = i0 + p;
        int c = (i < N_NODES) ? cnti[i] : 0;
        if (i < N_NODES) dinv[i] = rsqrtf(1.0f + (float)c);
        v[p] = (c + 7) & ~7;                 // padded row length
        tsum += v[p];
    }
    int sc = tsum;
#pragma unroll
    for (int off = 1; off < 64; off <<= 1) {
        int t = __shfl_up(sc, off, 64);
        if (lane >= off) sc += t;
    }
    if (lane == 63) wsum[wid] = sc;
    __syncthreads();
    int woff = 0;
    for (int w = 0; w < wid; ++w) woff += wsum[w];
    int excl = woff + sc - tsum;
#pragma unroll
    for (int p = 0; p < 4; ++p) {
        int i = i0 + p;
        if (i < N_NODES) rowptr[i] = excl;
        excl += v[p];
    }
    if (tid == 255) bsum[blockIdx.x] = woff + sc;   // padded block total
}

// -------- scan 2+3 merged: add block prefix; write pad entries (ZROW) --------
__global__ __launch_bounds__(256) void k_scan3(int* __restrict__ rowptr,
                                               const int* __restrict__ bsum,
                                               const int* __restrict__ cnti,
                                               ushort* __restrict__ csrc16) {
    __shared__ int soff;
    int tid = threadIdx.x;
    int chunk = blockIdx.x >> 2;          // which 1024-node chunk (0..48)
    if (tid < 64) {
        int v = (tid < chunk) ? bsum[tid] : 0;   // exclusive prefix
#pragma unroll
        for (int off = 32; off; off >>= 1) v += __shfl_xor(v, off, 64);
        if (tid == 0) soff = v;
    }
    __syncthreads();
    int i = blockIdx.x * 256 + tid;
    if (i < N_NODES) {
        int rp = rowptr[i] + soff;
        rowptr[i] = rp;
        int c  = cnti[i];
        int ce = (c + 7) & ~7;
        for (int p = c; p < ce; ++p) csrc16[rp + p] = (ushort)ZROW;
        if (i == N_NODES - 1) rowptr[N_NODES] = rp + ce;
    }
}

// ---- fused: blocks [0,NB_GEMM) gemm1 (y = fp8(dinv * xb@Wt1));  -------------
// ---- blocks [NB_GEMM,..) CSR fill (atomic-free) -----------------------------
__global__ __launch_bounds__(256) void k_gemm_fill(const ushort* __restrict__ Xb,
                                                   const ushort* __restrict__ Wt,
                                                   const float* __restrict__ dinv,
                                                   unsigned char* __restrict__ Y,
                                                   const int* __restrict__ src,
                                                   const int* __restrict__ dst,
                                                   const int* __restrict__ rowptr,
                                                   const ushort* __restrict__ slot16,
                                                   ushort* __restrict__ csrc16) {
    if (blockIdx.x >= NB_GEMM) {
        int e = (blockIdx.x - NB_GEMM) * 256 + threadIdx.x;
        if (e < N_EDGES) {
            int d = dst[e];
            int pos = rowptr[d] + (int)slot16[e];
            csrc16[pos] = (ushort)src[e];
        }
        return;
    }
    int tid  = threadIdx.x;
    int lane = tid & 63;
    int wv   = tid >> 6;            // 0..3
    int c0   = wv * 32;
    int lrow = lane & 31;
    int kgrp = lane >> 5;

    bf16x8 bfrag[8];
    {
        const ushort* wp = Wt + (size_t)(c0 + lrow) * HDIM + kgrp * 8;
#pragma unroll
        for (int kc = 0; kc < 8; ++kc) {
            BF8 t;
            t.q = *reinterpret_cast<const uint4*>(wp + kc * 16);
            bfrag[kc] = t.v;
        }
    }
#pragma unroll
    for (int chunk = 0; chunk < 2; ++chunk) {
        int m0 = blockIdx.x * 64 + chunk * 32;
        if (m0 >= N_NODES) return;
        int arow = m0 + lrow;
        if (arow > N_NODES - 1) arow = N_NODES - 1;
        const ushort* xp = Xb + (size_t)arow * HDIM + kgrp * 8;
        f32x16 acc;
#pragma unroll
        for (int i = 0; i < 16; ++i) acc[i] = 0.f;
#pragma unroll
        for (int kc = 0; kc < 8; ++kc) {
            BF8 a;
            a.q = *reinterpret_cast<const uint4*>(xp + kc * 16);
            acc = __builtin_amdgcn_mfma_f32_32x32x16_bf16(a.v, bfrag[kc], acc, 0, 0, 0);
        }
#pragma unroll
        for (int r = 0; r < 16; r += 2) {
            int row0 = m0 + (r & 3) + 8 * (r >> 2) + 4 * kgrp;
            float d0 = (row0     < N_NODES) ? dinv[row0]     : 0.f;
            float d1 = (row0 + 1 < N_NODES) ? dinv[row0 + 1] : 0.f;
            unsigned pk = (unsigned)__builtin_amdgcn_cvt_pk_fp8_f32(acc[r] * d0, acc[r + 1] * d1, 0, false);
            if (row0 < N_NODES)
                Y[(size_t)row0 * HDIM + c0 + lrow] = (unsigned char)(pk & 0xFF);
            if (row0 + 1 < N_NODES)
                Y[(size_t)(row0 + 1) * HDIM + c0 + lrow] = (unsigned char)((pk >> 8) & 0xFF);
        }
    }
}

// ---------------- plain MFMA GEMM (layer 2): y = fp8(dinv * X@W) -------------
__global__ __launch_bounds__(256) void k_gemm(const ushort* __restrict__ Xb,
                                              const ushort* __restrict__ Wt,
                                              const float* __restrict__ dinv,
                                              unsigned char* __restrict__ Y) {
    int tid  = threadIdx.x;
    int lane = tid & 63;
    int wv   = tid >> 6;
    int c0   = wv * 32;
    int lrow = lane & 31;
    int kgrp = lane >> 5;

    bf16x8 bfrag[8];
    {
        const ushort* wp = Wt + (size_t)(c0 + lrow) * HDIM + kgrp * 8;
#pragma unroll
        for (int kc = 0; kc < 8; ++kc) {
            BF8 t;
            t.q = *reinterpret_cast<const uint4*>(wp + kc * 16);
            bfrag[kc] = t.v;
        }
    }
#pragma unroll
    for (int chunk = 0; chunk < 2; ++chunk) {
        int m0 = blockIdx.x * 64 + chunk * 32;
        if (m0 >= N_NODES) return;
        int arow = m0 + lrow;
        if (arow > N_NODES - 1) arow = N_NODES - 1;
        const ushort* xp = Xb + (size_t)arow * HDIM + kgrp * 8;
        f32x16 acc;
#pragma unroll
        for (int i = 0; i < 16; ++i) acc[i] = 0.f;
#pragma unroll
        for (int kc = 0; kc < 8; ++kc) {
            BF8 a;
            a.q = *reinterpret_cast<const uint4*>(xp + kc * 16);
            acc = __builtin_amdgcn_mfma_f32_32x32x16_bf16(a.v, bfrag[kc], acc, 0, 0, 0);
        }
#pragma unroll
        for (int r = 0; r < 16; r += 2) {
            int row0 = m0 + (r & 3) + 8 * (r >> 2) + 4 * kgrp;
            float d0 = (row0     < N_NODES) ? dinv[row0]     : 0.f;
            float d1 = (row0 + 1 < N_NODES) ? dinv[row0 + 1] : 0.f;
            unsigned pk = (unsigned)__builtin_amdgcn_cvt_pk_fp8_f32(acc[r] * d0, acc[r + 1] * d1, 0, false);
            if (row0 < N_NODES)
                Y[(size_t)row0 * HDIM + c0 + lrow] = (unsigned char)(pk & 0xFF);
            if (row0 + 1 < N_NODES)
                Y[(size_t)(row0 + 1) * HDIM + c0 + lrow] = (unsigned char)((pk >> 8) & 0xFF);
        }
    }
}

// ------- aggregation: wave/node; rows padded to 8; y pre-scaled by dinv ------
__global__ __launch_bounds__(256) void k_agg(const unsigned char* __restrict__ y,
                                             const int* __restrict__ rowptr,
                                             const ushort* __restrict__ csrc16,
                                             const float* __restrict__ dinv,
                                             const float* __restrict__ bias,
                                             ushort* __restrict__ h) {
    int node = blockIdx.x * 4 + (threadIdx.x >> 6);
    if (node >= N_NODES) return;
    int lane = threadIdx.x & 63;
    int grp  = lane >> 5;           // 0..1: edge half
    int fl   = lane & 31;           // 4-feature slot within the row
    int e0 = rowptr[node], e1 = rowptr[node + 1];
    float di = dinv[node];
    float a0 = 0.f, a1 = 0.f, a2 = 0.f, a3 = 0.f;
    int j = e0;
    for (; j + 16 <= e1; j += 16) {       // 16 edges/iter: 8 per half
        uint4 iv = *reinterpret_cast<const uint4*>(csrc16 + j + grp * 8);
        int s[8];
        s[0] = iv.x & 0xFFFF; s[1] = iv.x >> 16;
        s[2] = iv.y & 0xFFFF; s[3] = iv.y >> 16;
        s[4] = iv.z & 0xFFFF; s[5] = iv.z >> 16;
        s[6] = iv.w & 0xFFFF; s[7] = iv.w >> 16;
        unsigned pkv[8];
#pragma unroll
        for (int k = 0; k < 8; ++k)
            pkv[k] = *reinterpret_cast<const unsigned*>(y + (size_t)s[k] * HDIM + fl * 4);
#pragma unroll
        for (int k = 0; k < 8; ++k) {
            f32x2 lo = __builtin_amdgcn_cvt_pk_f32_fp8(pkv[k], false);
            f32x2 hi = __builtin_amdgcn_cvt_pk_f32_fp8(pkv[k], true);
            a0 += lo[0]; a1 += lo[1]; a2 += hi[0]; a3 += hi[1];
        }
    }
    if (j < e1) {                          // exactly 8 left: 4 per half
        uint2 iv = *reinterpret_cast<const uint2*>(csrc16 + j + grp * 4);
        int s[4];
        s[0] = iv.x & 0xFFFF; s[1] = iv.x >> 16;
        s[2] = iv.y & 0xFFFF; s[3] = iv.y >> 16;
        unsigned pkv[4];
#pragma unroll
        for (int k = 0; k < 4; ++k)
            pkv[k] = *reinterpret_cast<const unsigned*>(y + (size_t)s[k] * HDIM + fl * 4);
#pragma unroll
        for (int k = 0; k < 4; ++k) {
            f32x2 lo = __builtin_amdgcn_cvt_pk_f32_fp8(pkv[k], false);
            f32x2 hi = __builtin_amdgcn_cvt_pk_f32_fp8(pkv[k], true);
            a0 += lo[0]; a1 += lo[1]; a2 += hi[0]; a3 += hi[1];
        }
    }
    // merge the two edge-halves
    a0 += __shfl_xor(a0, 32, 64);
    a1 += __shfl_xor(a1, 32, 64);
    a2 += __shfl_xor(a2, 32, 64);
    a3 += __shfl_xor(a3, 32, 64);
    // self-loop (y[node] already dinv-scaled) + final di scale + bias + relu
    {
        unsigned pk = *reinterpret_cast<const unsigned*>(y + (size_t)node * HDIM + fl * 4);
        f32x2 lo = __builtin_amdgcn_cvt_pk_f32_fp8(pk, false);
        f32x2 hi = __builtin_amdgcn_cvt_pk_f32_fp8(pk, true);
        a0 += lo[0]; a1 += lo[1]; a2 += hi[0]; a3 += hi[1];
    }
    float r0 = fmaxf(fmaf(a0, di, bias[fl * 4 + 0]), 0.f);
    float r1 = fmaxf(fmaf(a1, di, bias[fl * 4 + 1]), 0.f);
    float r2 = fmaxf(fmaf(a2, di, bias[fl * 4 + 2]), 0.f);
    float r3 = fmaxf(fmaf(a3, di, bias[fl * 4 + 3]), 0.f);
    if (grp == 0) {
        uint2 pk;
        pk.x = (unsigned)f2bf(r0) | ((unsigned)f2bf(r1) << 16);
        pk.y = (unsigned)f2bf(r2) | ((unsigned)f2bf(r3) << 16);
        *reinterpret_cast<uint2*>(h + (size_t)node * HDIM + fl * 4) = pk;
    }
}

// ---------------- mean-pool: sorted batch, run-length partial sums -----------
__global__ __launch_bounds__(256) void k_pool(const ushort* __restrict__ h2,
                                              const ushort* __restrict__ h1,
                                              const int* __restrict__ batch,
                                              float* __restrict__ hG) {
    int f  = threadIdx.x;                       // 0..255 (h2 | h1 concat)
    const ushort* srcp = (f < HDIM) ? h2 : h1;
    int ff = f & (HDIM - 1);
    int n0 = blockIdx.x * 32;
    int n1 = min(n0 + 32, N_NODES);
    int g = batch[n0];
    float run = 0.f;
    for (int n = n0; n < n1; ++n) {
        int gn = batch[n];
        if (gn != g) {
            atomicAdd(&hG[g * 256 + f], run);
            run = 0.f;
            g = gn;
        }
        run += bf2f(srcp[(size_t)n * HDIM + ff]);
    }
    atomicAdd(&hG[g * 256 + f], run);
}

// ---------------- finalize: counts via binary search (batch sorted) ----------
__global__ __launch_bounds__(256) void k_final(const float* __restrict__ hG,
                                               const int* __restrict__ batch,
                                               const float* __restrict__ Wl,
                                               const float* __restrict__ bl,
                                               float* __restrict__ outp) {
    __shared__ float sH[NGRAPH * 2 * HDIM];
    __shared__ float sL[NGRAPH * NCLS];
    __shared__ int   sStart[NGRAPH + 1];
    int tid = threadIdx.x;
    if (tid <= NGRAPH) {
        int lo = 0, hi = N_NODES;
        while (lo < hi) {
            int mid = (lo + hi) >> 1;
            if (batch[mid] < tid) lo = mid + 1; else hi = mid;
        }
        sStart[tid] = lo;
    }
    __syncthreads();
    for (int i = tid; i < NGRAPH * 2 * HDIM; i += 256) {
        int g = i >> 8;
        float cnt = (float)(sStart[g + 1] - sStart[g]);
        float m = hG[i] / fmaxf(cnt, 1.0f);
        sH[i] = m;
        outp[i] = m;
    }
    __syncthreads();
    if (tid < NGRAPH * NCLS) {
        int g = tid / NCLS, c = tid % NCLS;
        float acc = bl[c];
        for (int k = 0; k < 2 * HDIM; ++k)
            acc += sH[g * 256 + k] * Wl[k * NCLS + c];
        sL[tid] = acc;
    }
    __syncthreads();
    if (tid < NGRAPH) {
        float mx = -1e30f;
        for (int c = 0; c < NCLS; ++c) mx = fmaxf(mx, sL[tid * NCLS + c]);
        float se = 0.f;
        for (int c = 0; c < NCLS; ++c) se += expf(sL[tid * NCLS + c] - mx);
        float lse = logf(se) + mx;
        for (int c = 0; c < NCLS; ++c)
            outp[NGRAPH * 2 * HDIM + tid * NCLS + c] = sL[tid * NCLS + c] - lse;
    }
}

extern "C" void kernel_launch(void* const* d_in, const int* in_sizes, int n_in,
                              void* d_out, int out_size, void* d_ws, size_t ws_size,
                              hipStream_t stream) {
    const float* x    = (const float*)d_in[0];
    const int*   eidx = (const int*)d_in[1];
    const int*   batch= (const int*)d_in[2];
    const float* W1   = (const float*)d_in[3];
    const float* b1   = (const float*)d_in[4];
    const float* W2   = (const float*)d_in[5];
    const float* b2   = (const float*)d_in[6];
    const float* Wl   = (const float*)d_in[7];
    const float* bl   = (const float*)d_in[8];
    float* outp = (float*)d_out;

    const int* src = eidx;             // edge_index[0]
    const int* dst = eidx + N_EDGES;   // edge_index[1]

    char* ws = (char*)d_ws;
    size_t off = 0;
    auto alloc = [&](size_t bytes) -> char* {
        char* p = ws + off;
        off += (bytes + 255) & ~(size_t)255;
        return p;
    };
    ushort*        xb    = (ushort*)alloc((size_t)N_NODES * HDIM * 2);
    unsigned char* y     = (unsigned char*)alloc((size_t)(N_NODES + 1) * HDIM); // fp8 + zero row
    ushort*        h1    = (ushort*)alloc((size_t)N_NODES * HDIM * 2);
    ushort*        h2    = (ushort*)alloc((size_t)N_NODES * HDIM * 2);
    ushort*        Wt1   = (ushort*)alloc((size_t)HDIM * HDIM * 2);
    ushort*        Wt2   = (ushort*)alloc((size_t)HDIM * HDIM * 2);
    float*         dinv  = (float*) alloc((size_t)N_NODES * 4);
    int*           cnti  = (int*)   alloc((size_t)N_NODES * 4);
    int*           rowptr= (int*)   alloc((size_t)(N_NODES + 1) * 4);
    int*           bsum  = (int*)   alloc((size_t)NSCANBLK * 4);
    ushort*        slot16= (ushort*)alloc((size_t)N_EDGES * 2);
    ushort*        csrc16= (ushort*)alloc((size_t)(N_EDGES + 8 * N_NODES) * 2); // padded CSR
    float*         hG    = (float*) alloc((size_t)NGRAPH * 2 * HDIM * 4);

    k_zero     <<<(N_NODES + 255) / 256, 256, 0, stream>>>(cnti, hG);
    k_count_pre<<<NB_CNT + NB_PRE, 256, 0, stream>>>(dst, cnti, slot16,
                                                     x, xb, W1, W2, Wt1, Wt2, y);
    k_scan1<<<NSCANBLK, 256, 0, stream>>>(cnti, rowptr, bsum, dinv);
    k_scan3<<<(N_NODES + 255) / 256, 256, 0, stream>>>(rowptr, bsum, cnti, csrc16);

    k_gemm_fill<<<NB_GEMM + NB_EDGE, 256, 0, stream>>>(xb, Wt1, dinv, y,
                                                       src, dst, rowptr, slot16, csrc16);
    k_agg <<<(N_NODES + 3) / 4, 256, 0, stream>>>(y, rowptr, csrc16, dinv, b1, h1);
    k_gemm<<<NB_GEMM, 256, 0, stream>>>(h1, Wt2, dinv, y);
    k_agg <<<(N_NODES + 3) / 4, 256, 0, stream>>>(y, rowptr, csrc16, dinv, b2, h2);

    k_pool <<<(N_NODES + 31) / 32, 256, 0, stream>>>(h2, h1, batch, hG);
    k_final<<<1, 256, 0, stream>>>(hG, batch, Wl, bl, outp);

    (void)in_sizes; (void)n_in; (void)out_size; (void)ws_size;
}

// Round 19
// 167.680 us; speedup vs baseline: 1.0115x; 1.0115x over previous
//
#include <hip/hip_runtime.h>

#define N_NODES 50000
#define N_EDGES 800000
#define HDIM    128
#define NGRAPH  8
#define NCLS    5
#define ZROW    50000                                         // zero row in y
#define SCAN_CHUNK 1024
#define NSCANBLK ((N_NODES + SCAN_CHUNK - 1) / SCAN_CHUNK)   // 49
#define NB_GEMM  ((N_NODES + 63) / 64)                        // 782
#define NB_EDGE  ((N_EDGES + 255) / 256)                      // 3125
#define NB_CNT   ((N_EDGES / 8 + 255) / 256)                  // 391
#define NB_PRE   ((N_NODES * HDIM / 8 + 255) / 256)           // 3125

// ---- bf16 helpers (raw ushort storage, fp32 compute) ------------------------
__device__ __forceinline__ float bf2f(ushort u) {
    return __uint_as_float((unsigned int)u << 16);
}
__device__ __forceinline__ ushort f2bf(float f) {
    unsigned int u = __float_as_uint(f);
    u += 0x7FFFu + ((u >> 16) & 1u);      // round-to-nearest-even
    return (ushort)(u >> 16);
}

typedef __attribute__((ext_vector_type(8)))  __bf16 bf16x8;
typedef __attribute__((ext_vector_type(16))) float  f32x16;
typedef __attribute__((ext_vector_type(2)))  float  f32x2;
union BF8 { uint4 q; ushort u[8]; bf16x8 v; };

// ------- zero: cnti + hG (tiny; must precede fused count||pre) ---------------
__global__ __launch_bounds__(256) void k_zero(int* cnti, float* hG) {
    int i = blockIdx.x * blockDim.x + threadIdx.x;
    if (i < N_NODES) cnti[i] = 0;
    if (i < NGRAPH * 2 * HDIM) hG[i] = 0.0f;
}

// ------- fused: blocks [0,NB_CNT) = count+slot (8 edges/thread, FIRST so ----
// ------- atomics start immediately); blocks [NB_CNT,..) = pre (streaming) ----
__global__ __launch_bounds__(256) void k_count_pre(const int* __restrict__ dst,
                                                   int* cnti,
                                                   ushort* __restrict__ slot16,
                                                   const float* __restrict__ x,
                                                   ushort* __restrict__ xb,
                                                   const float* __restrict__ W1,
                                                   const float* __restrict__ W2,
                                                   ushort* __restrict__ Wt1,
                                                   ushort* __restrict__ Wt2,
                                                   unsigned char* __restrict__ y) {
    if (blockIdx.x < NB_CNT) {
        // ---- count path ----
        int e8 = blockIdx.x * 256 + threadIdx.x;
        if (e8 < N_EDGES / 8) {
            int4 d0 = reinterpret_cast<const int4*>(dst)[e8 * 2];
            int4 d1 = reinterpret_cast<const int4*>(dst)[e8 * 2 + 1];
            ushort4 s0, s1;
            s0.x = (ushort)atomicAdd(&cnti[d0.x], 1);
            s0.y = (ushort)atomicAdd(&cnti[d0.y], 1);
            s0.z = (ushort)atomicAdd(&cnti[d0.z], 1);
            s0.w = (ushort)atomicAdd(&cnti[d0.w], 1);
            s1.x = (ushort)atomicAdd(&cnti[d1.x], 1);
            s1.y = (ushort)atomicAdd(&cnti[d1.y], 1);
            s1.z = (ushort)atomicAdd(&cnti[d1.z], 1);
            s1.w = (ushort)atomicAdd(&cnti[d1.w], 1);
            reinterpret_cast<ushort4*>(slot16)[e8 * 2]     = s0;
            reinterpret_cast<ushort4*>(slot16)[e8 * 2 + 1] = s1;
        }
        return;
    }
    // ---- pre path ----
    int i = (blockIdx.x - NB_CNT) * 256 + threadIdx.x;
    if (i < 32) reinterpret_cast<unsigned*>(y + (size_t)ZROW * HDIM)[i] = 0u;
    if (i < HDIM * HDIM) {
        int k = i >> 7, c = i & (HDIM - 1);          // read W[k][c] coalesced
        Wt1[c * HDIM + k] = f2bf(W1[i]);
        Wt2[c * HDIM + k] = f2bf(W2[i]);
    }
    if ((size_t)i * 8 < (size_t)N_NODES * HDIM) {
        float4 f0 = reinterpret_cast<const float4*>(x)[i * 2];
        float4 f1 = reinterpret_cast<const float4*>(x)[i * 2 + 1];
        uint4 o;
        o.x = (unsigned)f2bf(f0.x) | ((unsigned)f2bf(f0.y) << 16);
        o.y = (unsigned)f2bf(f0.z) | ((unsigned)f2bf(f0.w) << 16);
        o.z = (unsigned)f2bf(f1.x) | ((unsigned)f2bf(f1.y) << 16);
        o.w = (unsigned)f2bf(f1.z) | ((unsigned)f2bf(f1.w) << 16);
        reinterpret_cast<uint4*>(xb)[i] = o;
    }
}

// -------- scan step 1: exclusive scan of CEIL8(in-degree) + dinv -------------
__global__ __launch_bounds__(256) void k_scan1(const int* __restrict__ cnti,
                                               int* __restrict__ rowptr,
                                               int* __restrict__ bsum,
                                               float* __restrict__ dinv) {
    __shared__ int wsum[4];
    int tid = threadIdx.x, lane = tid & 63, wid = tid >> 6;
    int i0 = blockIdx.x * SCAN_CHUNK + tid * 4;
    int v[4];
    int tsum = 0;
#pragma unroll
    for (int p = 0; p < 4; ++p) {
        int i = i0 + p;
        int c = (i < N_NODES) ? cnti[i] : 0;
        if (i < N_NODES) dinv[i] = rsqrtf(1.0f + (float)c);
        v[p] = (c + 7) & ~7;                 // padded row length
        tsum += v[p];
    }
    int sc = tsum;
#pragma unroll
    for (int off = 1; off < 64; off <<= 1) {
        int t = __shfl_up(sc, off, 64);
        if (lane >= off) sc += t;
    }
    if (lane == 63) wsum[wid] = sc;
    __syncthreads();
    int woff = 0;
    for (int w = 0; w < wid; ++w) woff += wsum[w];
    int excl = woff + sc - tsum;
#pragma unroll
    for (int p = 0; p < 4; ++p) {
        int i = i0 + p;
        if (i < N_NODES) rowptr[i] = excl;
        excl += v[p];
    }
    if (tid == 255) bsum[blockIdx.x] = woff + sc;   // padded block total
}

// -------- scan 2+3 merged: add block prefix; write pad entries (ZROW) --------
__global__ __launch_bounds__(256) void k_scan3(int* __restrict__ rowptr,
                                               const int* __restrict__ bsum,
                                               const int* __restrict__ cnti,
                                               ushort* __restrict__ csrc16) {
    __shared__ int soff;
    int tid = threadIdx.x;
    int chunk = blockIdx.x >> 2;          // which 1024-node chunk (0..48)
    if (tid < 64) {
        int v = (tid < chunk) ? bsum[tid] : 0;   // exclusive prefix
#pragma unroll
        for (int off = 32; off; off >>= 1) v += __shfl_xor(v, off, 64);
        if (tid == 0) soff = v;
    }
    __syncthreads();
    int i = blockIdx.x * 256 + tid;
    if (i < N_NODES) {
        int rp = rowptr[i] + soff;
        rowptr[i] = rp;
        int c  = cnti[i];
        int ce = (c + 7) & ~7;
        for (int p = c; p < ce; ++p) csrc16[rp + p] = (ushort)ZROW;
        if (i == N_NODES - 1) rowptr[N_NODES] = rp + ce;
    }
}

// ---- fused: blocks [0,NB_GEMM) gemm1 (y = fp8(dinv * xb@Wt1));  -------------
// ---- blocks [NB_GEMM,..) CSR fill (atomic-free) -----------------------------
__global__ __launch_bounds__(256) void k_gemm_fill(const ushort* __restrict__ Xb,
                                                   const ushort* __restrict__ Wt,
                                                   const float* __restrict__ dinv,
                                                   unsigned char* __restrict__ Y,
                                                   const int* __restrict__ src,
                                                   const int* __restrict__ dst,
                                                   const int* __restrict__ rowptr,
                                                   const ushort* __restrict__ slot16,
                                                   ushort* __restrict__ csrc16) {
    if (blockIdx.x >= NB_GEMM) {
        int e = (blockIdx.x - NB_GEMM) * 256 + threadIdx.x;
        if (e < N_EDGES) {
            int d = dst[e];
            int pos = rowptr[d] + (int)slot16[e];
            csrc16[pos] = (ushort)src[e];
        }
        return;
    }
    int tid  = threadIdx.x;
    int lane = tid & 63;
    int wv   = tid >> 6;            // 0..3
    int c0   = wv * 32;
    int lrow = lane & 31;
    int kgrp = lane >> 5;

    bf16x8 bfrag[8];
    {
        const ushort* wp = Wt + (size_t)(c0 + lrow) * HDIM + kgrp * 8;
#pragma unroll
        for (int kc = 0; kc < 8; ++kc) {
            BF8 t;
            t.q = *reinterpret_cast<const uint4*>(wp + kc * 16);
            bfrag[kc] = t.v;
        }
    }
#pragma unroll
    for (int chunk = 0; chunk < 2; ++chunk) {
        int m0 = blockIdx.x * 64 + chunk * 32;
        if (m0 >= N_NODES) return;
        int arow = m0 + lrow;
        if (arow > N_NODES - 1) arow = N_NODES - 1;
        const ushort* xp = Xb + (size_t)arow * HDIM + kgrp * 8;
        f32x16 acc;
#pragma unroll
        for (int i = 0; i < 16; ++i) acc[i] = 0.f;
#pragma unroll
        for (int kc = 0; kc < 8; ++kc) {
            BF8 a;
            a.q = *reinterpret_cast<const uint4*>(xp + kc * 16);
            acc = __builtin_amdgcn_mfma_f32_32x32x16_bf16(a.v, bfrag[kc], acc, 0, 0, 0);
        }
#pragma unroll
        for (int r = 0; r < 16; r += 2) {
            int row0 = m0 + (r & 3) + 8 * (r >> 2) + 4 * kgrp;
            float d0 = (row0     < N_NODES) ? dinv[row0]     : 0.f;
            float d1 = (row0 + 1 < N_NODES) ? dinv[row0 + 1] : 0.f;
            unsigned pk = (unsigned)__builtin_amdgcn_cvt_pk_fp8_f32(acc[r] * d0, acc[r + 1] * d1, 0, false);
            if (row0 < N_NODES)
                Y[(size_t)row0 * HDIM + c0 + lrow] = (unsigned char)(pk & 0xFF);
            if (row0 + 1 < N_NODES)
                Y[(size_t)(row0 + 1) * HDIM + c0 + lrow] = (unsigned char)((pk >> 8) & 0xFF);
        }
    }
}

// ---------------- plain MFMA GEMM (layer 2): y = fp8(dinv * X@W) -------------
__global__ __launch_bounds__(256) void k_gemm(const ushort* __restrict__ Xb,
                                              const ushort* __restrict__ Wt,
                                              const float* __restrict__ dinv,
                                              unsigned char* __restrict__ Y) {
    int tid  = threadIdx.x;
    int lane = tid & 63;
    int wv   = tid >> 6;
    int c0   = wv * 32;
    int lrow = lane & 31;
    int kgrp = lane >> 5;

    bf16x8 bfrag[8];
    {
        const ushort* wp = Wt + (size_t)(c0 + lrow) * HDIM + kgrp * 8;
#pragma unroll
        for (int kc = 0; kc < 8; ++kc) {
            BF8 t;
            t.q = *reinterpret_cast<const uint4*>(wp + kc * 16);
            bfrag[kc] = t.v;
        }
    }
#pragma unroll
    for (int chunk = 0; chunk < 2; ++chunk) {
        int m0 = blockIdx.x * 64 + chunk * 32;
        if (m0 >= N_NODES) return;
        int arow = m0 + lrow;
        if (arow > N_NODES - 1) arow = N_NODES - 1;
        const ushort* xp = Xb + (size_t)arow * HDIM + kgrp * 8;
        f32x16 acc;
#pragma unroll
        for (int i = 0; i < 16; ++i) acc[i] = 0.f;
#pragma unroll
        for (int kc = 0; kc < 8; ++kc) {
            BF8 a;
            a.q = *reinterpret_cast<const uint4*>(xp + kc * 16);
            acc = __builtin_amdgcn_mfma_f32_32x32x16_bf16(a.v, bfrag[kc], acc, 0, 0, 0);
        }
#pragma unroll
        for (int r = 0; r < 16; r += 2) {
            int row0 = m0 + (r & 3) + 8 * (r >> 2) + 4 * kgrp;
            float d0 = (row0     < N_NODES) ? dinv[row0]     : 0.f;
            float d1 = (row0 + 1 < N_NODES) ? dinv[row0 + 1] : 0.f;
            unsigned pk = (unsigned)__builtin_amdgcn_cvt_pk_fp8_f32(acc[r] * d0, acc[r + 1] * d1, 0, false);
            if (row0 < N_NODES)
                Y[(size_t)row0 * HDIM + c0 + lrow] = (unsigned char)(pk & 0xFF);
            if (row0 + 1 < N_NODES)
                Y[(size_t)(row0 + 1) * HDIM + c0 + lrow] = (unsigned char)((pk >> 8) & 0xFF);
        }
    }
}

// ------- aggregation: wave/node; rows padded to 8; y pre-scaled by dinv ------
__global__ __launch_bounds__(256) void k_agg(const unsigned char* __restrict__ y,
                                             const int* __restrict__ rowptr,
                                             const ushort* __restrict__ csrc16,
                                             const float* __restrict__ dinv,
                                             const float* __restrict__ bias,
                                             ushort* __restrict__ h) {
    int node = blockIdx.x * 4 + (threadIdx.x >> 6);
    if (node >= N_NODES) return;
    int lane = threadIdx.x & 63;
    int grp  = lane >> 5;           // 0..1: edge half
    int fl   = lane & 31;           // 4-feature slot within the row
    int e0 = rowptr[node], e1 = rowptr[node + 1];
    float di = dinv[node];
    float a0 = 0.f, a1 = 0.f, a2 = 0.f, a3 = 0.f;
    int j = e0;
    for (; j + 16 <= e1; j += 16) {       // 16 edges/iter: 8 per half
        uint4 iv = *reinterpret_cast<const uint4*>(csrc16 + j + grp * 8);
        int s[8];
        s[0] = iv.x & 0xFFFF; s[1] = iv.x >> 16;
        s[2] = iv.y & 0xFFFF; s[3] = iv.y >> 16;
        s[4] = iv.z & 0xFFFF; s[5] = iv.z >> 16;
        s[6] = iv.w & 0xFFFF; s[7] = iv.w >> 16;
        unsigned pkv[8];
#pragma unroll
        for (int k = 0; k < 8; ++k)
            pkv[k] = *reinterpret_cast<const unsigned*>(y + (size_t)s[k] * HDIM + fl * 4);
#pragma unroll
        for (int k = 0; k < 8; ++k) {
            f32x2 lo = __builtin_amdgcn_cvt_pk_f32_fp8(pkv[k], false);
            f32x2 hi = __builtin_amdgcn_cvt_pk_f32_fp8(pkv[k], true);
            a0 += lo[0]; a1 += lo[1]; a2 += hi[0]; a3 += hi[1];
        }
    }
    if (j < e1) {                          // exactly 8 left: 4 per half
        uint2 iv = *reinterpret_cast<const uint2*>(csrc16 + j + grp * 4);
        int s[4];
        s[0] = iv.x & 0xFFFF; s[1] = iv.x >> 16;
        s[2] = iv.y & 0xFFFF; s[3] = iv.y >> 16;
        unsigned pkv[4];
#pragma unroll
        for (int k = 0; k < 4; ++k)
            pkv[k] = *reinterpret_cast<const unsigned*>(y + (size_t)s[k] * HDIM + fl * 4);
#pragma unroll
        for (int k = 0; k < 4; ++k) {
            f32x2 lo = __builtin_amdgcn_cvt_pk_f32_fp8(pkv[k], false);
            f32x2 hi = __builtin_amdgcn_cvt_pk_f32_fp8(pkv[k], true);
            a0 += lo[0]; a1 += lo[1]; a2 += hi[0]; a3 += hi[1];
        }
    }
    // merge the two edge-halves
    a0 += __shfl_xor(a0, 32, 64);
    a1 += __shfl_xor(a1, 32, 64);
    a2 += __shfl_xor(a2, 32, 64);
    a3 += __shfl_xor(a3, 32, 64);
    // self-loop (y[node] already dinv-scaled) + final di scale + bias + relu
    {
        unsigned pk = *reinterpret_cast<const unsigned*>(y + (size_t)node * HDIM + fl * 4);
        f32x2 lo = __builtin_amdgcn_cvt_pk_f32_fp8(pk, false);
        f32x2 hi = __builtin_amdgcn_cvt_pk_f32_fp8(pk, true);
        a0 += lo[0]; a1 += lo[1]; a2 += hi[0]; a3 += hi[1];
    }
    float r0 = fmaxf(fmaf(a0, di, bias[fl * 4 + 0]), 0.f);
    float r1 = fmaxf(fmaf(a1, di, bias[fl * 4 + 1]), 0.f);
    float r2 = fmaxf(fmaf(a2, di, bias[fl * 4 + 2]), 0.f);
    float r3 = fmaxf(fmaf(a3, di, bias[fl * 4 + 3]), 0.f);
    if (grp == 0) {
        uint2 pk;
        pk.x = (unsigned)f2bf(r0) | ((unsigned)f2bf(r1) << 16);
        pk.y = (unsigned)f2bf(r2) | ((unsigned)f2bf(r3) << 16);
        *reinterpret_cast<uint2*>(h + (size_t)node * HDIM + fl * 4) = pk;
    }
}

// ---------------- mean-pool: sorted batch, run-length partial sums -----------
__global__ __launch_bounds__(256) void k_pool(const ushort* __restrict__ h2,
                                              const ushort* __restrict__ h1,
                                              const int* __restrict__ batch,
                                              float* __restrict__ hG) {
    int f  = threadIdx.x;                       // 0..255 (h2 | h1 concat)
    const ushort* srcp = (f < HDIM) ? h2 : h1;
    int ff = f & (HDIM - 1);
    int n0 = blockIdx.x * 32;
    int n1 = min(n0 + 32, N_NODES);
    int g = batch[n0];
    float run = 0.f;
    for (int n = n0; n < n1; ++n) {
        int gn = batch[n];
        if (gn != g) {
            atomicAdd(&hG[g * 256 + f], run);
            run = 0.f;
            g = gn;
        }
        run += bf2f(srcp[(size_t)n * HDIM + ff]);
    }
    atomicAdd(&hG[g * 256 + f], run);
}

// ---------------- finalize: counts via binary search (batch sorted) ----------
__global__ __launch_bounds__(256) void k_final(const float* __restrict__ hG,
                                               const int* __restrict__ batch,
                                               const float* __restrict__ Wl,
                                               const float* __restrict__ bl,
                                               float* __restrict__ outp) {
    __shared__ float sH[NGRAPH * 2 * HDIM];
    __shared__ float sL[NGRAPH * NCLS];
    __shared__ int   sStart[NGRAPH + 1];
    int tid = threadIdx.x;
    if (tid <= NGRAPH) {
        int lo = 0, hi = N_NODES;
        while (lo < hi) {
            int mid = (lo + hi) >> 1;
            if (batch[mid] < tid) lo = mid + 1; else hi = mid;
        }
        sStart[tid] = lo;
    }
    __syncthreads();
    for (int i = tid; i < NGRAPH * 2 * HDIM; i += 256) {
        int g = i >> 8;
        float cnt = (float)(sStart[g + 1] - sStart[g]);
        float m = hG[i] / fmaxf(cnt, 1.0f);
        sH[i] = m;
        outp[i] = m;
    }
    __syncthreads();
    if (tid < NGRAPH * NCLS) {
        int g = tid / NCLS, c = tid % NCLS;
        float acc = bl[c];
        for (int k = 0; k < 2 * HDIM; ++k)
            acc += sH[g * 256 + k] * Wl[k * NCLS + c];
        sL[tid] = acc;
    }
    __syncthreads();
    if (tid < NGRAPH) {
        float mx = -1e30f;
        for (int c = 0; c < NCLS; ++c) mx = fmaxf(mx, sL[tid * NCLS + c]);
        float se = 0.f;
        for (int c = 0; c < NCLS; ++c) se += expf(sL[tid * NCLS + c] - mx);
        float lse = logf(se) + mx;
        for (int c = 0; c < NCLS; ++c)
            outp[NGRAPH * 2 * HDIM + tid * NCLS + c] = sL[tid * NCLS + c] - lse;
    }
}

extern "C" void kernel_launch(void* const* d_in, const int* in_sizes, int n_in,
                              void* d_out, int out_size, void* d_ws, size_t ws_size,
                              hipStream_t stream) {
    const float* x    = (const float*)d_in[0];
    const int*   eidx = (const int*)d_in[1];
    const int*   batch= (const int*)d_in[2];
    const float* W1   = (const float*)d_in[3];
    const float* b1   = (const float*)d_in[4];
    const float* W2   = (const float*)d_in[5];
    const float* b2   = (const float*)d_in[6];
    const float* Wl   = (const float*)d_in[7];
    const float* bl   = (const float*)d_in[8];
    float* outp = (float*)d_out;

    const int* src = eidx;             // edge_index[0]
    const int* dst = eidx + N_EDGES;   // edge_index[1]

    char* ws = (char*)d_ws;
    size_t off = 0;
    auto alloc = [&](size_t bytes) -> char* {
        char* p = ws + off;
        off += (bytes + 255) & ~(size_t)255;
        return p;
    };
    ushort*        xb    = (ushort*)alloc((size_t)N_NODES * HDIM * 2);
    unsigned char* y     = (unsigned char*)alloc((size_t)(N_NODES + 1) * HDIM); // fp8 + zero row
    ushort*        h1    = (ushort*)alloc((size_t)N_NODES * HDIM * 2);
    ushort*        h2    = (ushort*)alloc((size_t)N_NODES * HDIM * 2);
    ushort*        Wt1   = (ushort*)alloc((size_t)HDIM * HDIM * 2);
    ushort*        Wt2   = (ushort*)alloc((size_t)HDIM * HDIM * 2);
    float*         dinv  = (float*) alloc((size_t)N_NODES * 4);
    int*           cnti  = (int*)   alloc((size_t)N_NODES * 4);
    int*           rowptr= (int*)   alloc((size_t)(N_NODES + 1) * 4);
    int*           bsum  = (int*)   alloc((size_t)NSCANBLK * 4);
    ushort*        slot16= (ushort*)alloc((size_t)N_EDGES * 2);
    ushort*        csrc16= (ushort*)alloc((size_t)(N_EDGES + 8 * N_NODES) * 2); // padded CSR
    float*         hG    = (float*) alloc((size_t)NGRAPH * 2 * HDIM * 4);

    k_zero     <<<(N_NODES + 255) / 256, 256, 0, stream>>>(cnti, hG);
    k_count_pre<<<NB_CNT + NB_PRE, 256, 0, stream>>>(dst, cnti, slot16,
                                                     x, xb, W1, W2, Wt1, Wt2, y);
    k_scan1<<<NSCANBLK, 256, 0, stream>>>(cnti, rowptr, bsum, dinv);
    k_scan3<<<(N_NODES + 255) / 256, 256, 0, stream>>>(rowptr, bsum, cnti, csrc16);

    k_gemm_fill<<<NB_GEMM + NB_EDGE, 256, 0, stream>>>(xb, Wt1, dinv, y,
                                                       src, dst, rowptr, slot16, csrc16);
    k_agg <<<(N_NODES + 3) / 4, 256, 0, stream>>>(y, rowptr, csrc16, dinv, b1, h1);
    k_gemm<<<NB_GEMM, 256, 0, stream>>>(h1, Wt2, dinv, y);
    k_agg <<<(N_NODES + 3) / 4, 256, 0, stream>>>(y, rowptr, csrc16, dinv, b2, h2);

    k_pool <<<(N_NODES + 31) / 32, 256, 0, stream>>>(h2, h1, batch, hG);
    k_final<<<1, 256, 0, stream>>>(hG, batch, Wl, bl, outp);

    (void)in_sizes; (void)n_in; (void)out_size; (void)ws_size;
}